// Round 3
// baseline (419.766 us; speedup 1.0000x reference)
//
#include <hip/hip_runtime.h>
#include <math.h>

// Problem constants
#define LSEQ 512
#define KNN 30
#define NNODES 4096   // B*L = 8*512

// agg_edge scratch: [4096][33], fully rewritten by kernel1 every launch
__device__ float g_agg[NNODES * 33];

__device__ __forceinline__ unsigned long long shfl_xor_u64(unsigned long long v, int m) {
  unsigned lo = (unsigned)__shfl_xor((int)(unsigned)(v & 0xFFFFFFFFull), m, 64);
  unsigned hi = (unsigned)__shfl_xor((int)(unsigned)(v >> 32), m, 64);
  return ((unsigned long long)hi << 32) | lo;
}

// ---------------------------------------------------------------------------
// Kernel 1: KNN (k=30 smallest d2 per center, self excluded) fused with
// pair_feat gather + mean -> g_agg[n][0..31], mean dist0 -> g_agg[n][32]
// One wave per center node; 4 centers per 256-thread block.
// 1024 blocks = 4 blocks/CU, 16 waves/CU.
// ---------------------------------------------------------------------------
__global__ __launch_bounds__(256) void knn_agg_kernel(
    const float* __restrict__ t, const float* __restrict__ pair_feat) {
  __shared__ float sx[LSEQ], sy[LSEQ], sz[LSEQ], sq[LSEQ];
  __shared__ int nbr[4][KNN];
  const int blk = blockIdx.x;        // 0..1023
  const int tid = threadIdx.x;
  const int b = blk >> 7;            // 128 blocks per batch (512/4)
  // stage batch positions (SoA for conflict-free lane-strided reads)
  for (int j = tid; j < LSEQ; j += 256) {
    float x = t[(b * LSEQ + j) * 3 + 0];
    float y = t[(b * LSEQ + j) * 3 + 1];
    float z = t[(b * LSEQ + j) * 3 + 2];
    sx[j] = x; sy[j] = y; sz[j] = z;
    sq[j] = x * x + y * y + z * z;   // same formula/order as reference
  }
  __syncthreads();
  const int w = tid >> 6;            // wave id 0..3
  const int lane = tid & 63;
  const int i = blk * 4 + w;         // global center 0..4095 (never crosses batch)
  const int il = i & (LSEQ - 1);     // local center
  const float xi = sx[il], yi = sy[il], zi = sz[il], sqi = sq[il];

  // each lane owns 8 candidates j = lane + 64*m, packed as orderable u64 keys
  unsigned long long k64[8];
#pragma unroll
  for (int m = 0; m < 8; ++m) {
    int j = lane + 64 * m;
    float d2 = sqi + sq[j] - 2.0f * (xi * sx[j] + yi * sy[j] + zi * sz[j]);
    if (j == il) d2 = 1e30f;         // self-loop exclusion (ref adds 1e10)
    unsigned u = __float_as_uint(d2);
    // total-order transform (handles potential tiny negative d2 from cancellation)
    u = (u & 0x80000000u) ? ~u : (u | 0x80000000u);
    k64[m] = ((unsigned long long)u << 32) | (unsigned)j;  // low index wins ties (JAX)
  }
  unsigned long long lbest = k64[0];
#pragma unroll
  for (int m = 1; m < 8; ++m) lbest = (k64[m] < lbest) ? k64[m] : lbest;

  // 30 iterations of wave-wide argmin
  for (int it = 0; it < KNN; ++it) {
    unsigned long long v = lbest;
#pragma unroll
    for (int off = 32; off >= 1; off >>= 1) {
      unsigned long long o = shfl_xor_u64(v, off);
      v = (o < v) ? o : v;
    }
    int jwin = (int)(v & 0xFFFFFFFFull);
    if (lane == it) nbr[w][it] = jwin;              // per-wave list (in-order DS)
    if ((jwin & 63) == lane) {                      // winner lane retires its element
      k64[jwin >> 6] = ~0ull;
      lbest = k64[0];
#pragma unroll
      for (int m = 1; m < 8; ++m) lbest = (k64[m] < lbest) ? k64[m] : lbest;
    }
  }

  // gather pair_feat[b, src, dst, :] and average over the 30 neighbors.
  // lanes 0..31 handle even k (channel = lane), lanes 32..63 odd k.
  float acc = 0.0f;
  const int half = lane >> 5;
  const int c = lane & 31;
  const int base_b = b * LSEQ;
#pragma unroll
  for (int itr = 0; itr < KNN / 2; ++itr) {
    int k = itr * 2 + half;
    int j = nbr[w][k];
    acc += pair_feat[((base_b + j) * LSEQ + il) * 32 + c];
  }
  float other = __shfl_xor(acc, 32, 64);
  float tot = acc + other;
  if (lane < 32) g_agg[i * 33 + c] = tot * (1.0f / KNN);

  // mean initial distance over neighbors
  float dval = 0.0f;
  if (lane < KNN) {
    int j = nbr[w][lane];
    float dx = xi - sx[j], dy = yi - sy[j], dz = zi - sz[j];
    dval = sqrtf(dx * dx + dy * dy + dz * dz);
  }
#pragma unroll
  for (int off = 32; off >= 1; off >>= 1) dval += __shfl_xor(dval, off, 64);
  if (lane == 0) g_agg[i * 33 + 32] = dval * (1.0f / KNN);
}

// ---------------------------------------------------------------------------
// Kernel 2: 4 layers of the node MLP, fused (per-node chain, no grid sync).
//   x <- relu([x, agg] @ w1[l] + b1[l]) @ w2[l] + b2[l]
// 16 nodes per block, 256 blocks (1 block/CU on all 256 CUs — the previous
// 128-block shape left half the chip idle), 256 threads, 2x4 micro-tiles.
// K of GEMM1 padded 161 -> 192 with zeroed nf columns (weight rows clamped).
// LDS strides chosen for 16B alignment + bank spread: nf 196, h/w 132.
// ---------------------------------------------------------------------------
#define MT 16     // nodes per block
#define NFS 196
#define HS 132
#define WSS 132

__global__ __launch_bounds__(256) void node_mlp_kernel(
    const float* __restrict__ res_feat,
    const float* __restrict__ w1, const float* __restrict__ b1,
    const float* __restrict__ w2, const float* __restrict__ b2,
    float* __restrict__ out) {
  __shared__ float nf[MT * NFS];     // [16][196]: x(128) | agg(33) | zero pad
  __shared__ float hb[MT * HS];      // [16][132]: hidden
  __shared__ float wbuf[32 * WSS];   // [32][132]: weight K-chunk
  const int tid = threadIdx.x;
  const int node0 = blockIdx.x * MT;
  const int tx = tid & 31, ty = tid >> 5;   // ty 0..7
  const int c0 = tx * 4, r0 = ty * 2;       // 2x4 micro-tile

  // stage x tile (coalesced float4): 16*32 = 512 float4, 2 rounds
#pragma unroll
  for (int q = 0; q < 2; ++q) {
    int f4 = tid + 256 * q;
    int r = f4 >> 5, c4 = f4 & 31;
    *(float4*)&nf[r * NFS + c4 * 4] =
        *(const float4*)&res_feat[(node0 + r) * 128 + c4 * 4];
  }
  // stage agg tile + zero the K padding (cols 161..191)
  for (int idx = tid; idx < MT * 33; idx += 256) {
    int r = idx / 33, cc = idx - r * 33;
    nf[r * NFS + 128 + cc] = g_agg[(node0 + r) * 33 + cc];
  }
  for (int idx = tid; idx < MT * 31; idx += 256) {
    int r = idx / 31, cc = idx - r * 31;
    nf[r * NFS + 161 + cc] = 0.0f;
  }
  __syncthreads();

  for (int l = 0; l < 4; ++l) {
    // ---- GEMM1: h = relu(nf @ W1 + b1), K = 192 (padded from 161) ----
    const float* W1 = w1 + l * 161 * 128;
    float4 acc[2];
    float4 bin = *(const float4*)&b1[l * 128 + c0];
#pragma unroll
    for (int ii = 0; ii < 2; ++ii) acc[ii] = bin;
    for (int kc = 0; kc < 6; ++kc) {
      __syncthreads();  // previous chunk readers done
#pragma unroll
      for (int q = 0; q < 4; ++q) {
        int f4 = tid + 256 * q;
        int kk = f4 >> 5, c4 = f4 & 31;
        int row = kc * 32 + kk;
        row = row > 160 ? 160 : row;   // clamp: avoids OOB, nf col is 0 anyway
        *(float4*)&wbuf[kk * WSS + c4 * 4] = *(const float4*)&W1[row * 128 + c4 * 4];
      }
      __syncthreads();
#pragma unroll
      for (int k4 = 0; k4 < 8; ++k4) {
        float4 av[2], wv[4];
#pragma unroll
        for (int ii = 0; ii < 2; ++ii)
          av[ii] = *(const float4*)&nf[(r0 + ii) * NFS + kc * 32 + k4 * 4];
#pragma unroll
        for (int q = 0; q < 4; ++q)
          wv[q] = *(const float4*)&wbuf[(k4 * 4 + q) * WSS + c0];
#pragma unroll
        for (int ii = 0; ii < 2; ++ii) {
          const float* ap = (const float*)&av[ii];
#pragma unroll
          for (int q = 0; q < 4; ++q) {
            acc[ii].x = fmaf(ap[q], wv[q].x, acc[ii].x);
            acc[ii].y = fmaf(ap[q], wv[q].y, acc[ii].y);
            acc[ii].z = fmaf(ap[q], wv[q].z, acc[ii].z);
            acc[ii].w = fmaf(ap[q], wv[q].w, acc[ii].w);
          }
        }
      }
    }
    // relu -> hidden tile
#pragma unroll
    for (int ii = 0; ii < 2; ++ii) {
      float4 v = acc[ii];
      v.x = fmaxf(v.x, 0.0f); v.y = fmaxf(v.y, 0.0f);
      v.z = fmaxf(v.z, 0.0f); v.w = fmaxf(v.w, 0.0f);
      *(float4*)&hb[(r0 + ii) * HS + c0] = v;
    }

    // ---- GEMM2: x = h @ W2 + b2, K = 128 ----
    const float* W2 = w2 + l * 128 * 128;
    float4 acc2[2];
    float4 bin2 = *(const float4*)&b2[l * 128 + c0];
#pragma unroll
    for (int ii = 0; ii < 2; ++ii) acc2[ii] = bin2;
    for (int kc = 0; kc < 4; ++kc) {
      __syncthreads();  // also orders hb writes before hb reads
#pragma unroll
      for (int q = 0; q < 4; ++q) {
        int f4 = tid + 256 * q;
        int kk = f4 >> 5, c4 = f4 & 31;
        int row = kc * 32 + kk;
        *(float4*)&wbuf[kk * WSS + c4 * 4] = *(const float4*)&W2[row * 128 + c4 * 4];
      }
      __syncthreads();
#pragma unroll
      for (int k4 = 0; k4 < 8; ++k4) {
        float4 av[2], wv[4];
#pragma unroll
        for (int ii = 0; ii < 2; ++ii)
          av[ii] = *(const float4*)&hb[(r0 + ii) * HS + kc * 32 + k4 * 4];
#pragma unroll
        for (int q = 0; q < 4; ++q)
          wv[q] = *(const float4*)&wbuf[(k4 * 4 + q) * WSS + c0];
#pragma unroll
        for (int ii = 0; ii < 2; ++ii) {
          const float* ap = (const float*)&av[ii];
#pragma unroll
          for (int q = 0; q < 4; ++q) {
            acc2[ii].x = fmaf(ap[q], wv[q].x, acc2[ii].x);
            acc2[ii].y = fmaf(ap[q], wv[q].y, acc2[ii].y);
            acc2[ii].z = fmaf(ap[q], wv[q].z, acc2[ii].z);
            acc2[ii].w = fmaf(ap[q], wv[q].w, acc2[ii].w);
          }
        }
      }
    }
    if (l < 3) {
      // write next-layer x into nf (no conflicting readers until next staging sync)
#pragma unroll
      for (int ii = 0; ii < 2; ++ii)
        *(float4*)&nf[(r0 + ii) * NFS + c0] = acc2[ii];
    } else {
#pragma unroll
      for (int ii = 0; ii < 2; ++ii)
        *(float4*)&out[(node0 + r0 + ii) * 128 + c0] = acc2[ii];
    }
  }
}

// ---------------------------------------------------------------------------
extern "C" void kernel_launch(void* const* d_in, const int* in_sizes, int n_in,
                              void* d_out, int out_size, void* d_ws, size_t ws_size,
                              hipStream_t stream) {
  // setup_inputs order:
  // 0:R 1:t 2:res_feat 3:pair_feat 4:mask_res 5:coord_w1 6:coord_b1 7:coord_w2
  // 8:coord_b2 9:node_w1 10:node_b1 11:node_w2 12:node_b2
  // (R, mask_res and all coord_* are dead code for the returned x.)
  const float* t         = (const float*)d_in[1];
  const float* res_feat  = (const float*)d_in[2];
  const float* pair_feat = (const float*)d_in[3];
  const float* nw1       = (const float*)d_in[9];
  const float* nb1       = (const float*)d_in[10];
  const float* nw2       = (const float*)d_in[11];
  const float* nb2       = (const float*)d_in[12];
  float* out = (float*)d_out;
  (void)in_sizes; (void)n_in; (void)out_size; (void)d_ws; (void)ws_size;

  knn_agg_kernel<<<1024, 256, 0, stream>>>(t, pair_feat);
  node_mlp_kernel<<<NNODES / MT, 256, 0, stream>>>(res_feat, nw1, nb1, nw2, nb2, out);
}

// Round 7
// 411.203 us; speedup vs baseline: 1.0208x; 1.0208x over previous
//
#include <hip/hip_runtime.h>
#include <math.h>

// Problem constants
#define LSEQ 512
#define KNN 30
#define NNODES 4096   // B*L = 8*512

// agg_edge scratch: [4096][33], fully rewritten by kernel1 every launch
__device__ float g_agg[NNODES * 33];

// ---------------------------------------------------------------------------
// DPP-based wave64 min-reduce step for u64 keys (all-VALU, no LDS).
// bound_ctrl=false + old=own value => invalid lanes fold min(v,v)=v.
// ---------------------------------------------------------------------------
template <int CTRL>
__device__ __forceinline__ unsigned long long dpp_min(unsigned long long v) {
  int lo = (int)(unsigned)(v & 0xFFFFFFFFull);
  int hi = (int)(unsigned)(v >> 32);
  int plo = __builtin_amdgcn_update_dpp(lo, lo, CTRL, 0xF, 0xF, false);
  int phi = __builtin_amdgcn_update_dpp(hi, hi, CTRL, 0xF, 0xF, false);
  unsigned long long o = ((unsigned long long)(unsigned)phi << 32) | (unsigned)plo;
  return (o < v) ? o : v;
}

// ---------------------------------------------------------------------------
// Kernel 1: KNN (k=30 smallest d2 per center, self excluded) fused with
// pair_feat gather + mean -> g_agg[n][0..31], mean dist0 -> g_agg[n][32]
// One wave per center node; 4 centers per 256-thread block. 1024 blocks.
// Argmin via DPP (row_shr 1/2/4/8 + row_bcast15/31 -> lane63, readlane bcast).
// ---------------------------------------------------------------------------
__global__ __launch_bounds__(256) void knn_agg_kernel(
    const float* __restrict__ t, const float* __restrict__ pair_feat) {
  __shared__ float sx[LSEQ], sy[LSEQ], sz[LSEQ], sq[LSEQ];
  __shared__ int nbr[4][KNN];
  const int blk = blockIdx.x;        // 0..1023
  const int tid = threadIdx.x;
  const int b = blk >> 7;            // 128 blocks per batch (512/4)
  // stage batch positions (SoA for conflict-free lane-strided reads)
  for (int j = tid; j < LSEQ; j += 256) {
    float x = t[(b * LSEQ + j) * 3 + 0];
    float y = t[(b * LSEQ + j) * 3 + 1];
    float z = t[(b * LSEQ + j) * 3 + 2];
    sx[j] = x; sy[j] = y; sz[j] = z;
    sq[j] = x * x + y * y + z * z;   // same formula/order as reference
  }
  __syncthreads();
  const int w = tid >> 6;            // wave id 0..3
  const int lane = tid & 63;
  const int i = blk * 4 + w;         // global center 0..4095 (never crosses batch)
  const int il = i & (LSEQ - 1);     // local center
  const float xi = sx[il], yi = sy[il], zi = sz[il], sqi = sq[il];

  // each lane owns 8 candidates j = lane + 64*m, packed as orderable u64 keys
  unsigned long long k64[8];
#pragma unroll
  for (int m = 0; m < 8; ++m) {
    int j = lane + 64 * m;
    float d2 = sqi + sq[j] - 2.0f * (xi * sx[j] + yi * sy[j] + zi * sz[j]);
    if (j == il) d2 = 1e30f;         // self-loop exclusion (ref adds 1e10)
    unsigned u = __float_as_uint(d2);
    // total-order transform (handles potential tiny negative d2 from cancellation)
    u = (u & 0x80000000u) ? ~u : (u | 0x80000000u);
    k64[m] = ((unsigned long long)u << 32) | (unsigned)j;  // low index wins ties (JAX)
  }
  unsigned long long lbest = k64[0];
#pragma unroll
  for (int m = 1; m < 8; ++m) lbest = (k64[m] < lbest) ? k64[m] : lbest;

  // 30 iterations of wave-wide argmin, DPP reduce (~all-VALU, lane63 holds min)
  for (int it = 0; it < KNN; ++it) {
    unsigned long long v = lbest;
    v = dpp_min<0x111>(v);   // row_shr:1
    v = dpp_min<0x112>(v);   // row_shr:2
    v = dpp_min<0x114>(v);   // row_shr:4
    v = dpp_min<0x118>(v);   // row_shr:8  -> lane15 of each row has row-min
    v = dpp_min<0x142>(v);   // row_bcast15 -> lane31/63 combine two rows
    v = dpp_min<0x143>(v);   // row_bcast31 -> lane63 has full-wave min
    int jwin = __builtin_amdgcn_readlane((int)(unsigned)(v & 0xFFFFFFFFull), 63);
    if (lane == 0) nbr[w][it] = jwin;               // per-wave list (in-order DS)
    if ((jwin & 63) == lane) {                      // winner lane retires its element
      k64[jwin >> 6] = ~0ull;
      lbest = k64[0];
#pragma unroll
      for (int m = 1; m < 8; ++m) lbest = (k64[m] < lbest) ? k64[m] : lbest;
    }
  }

  // gather pair_feat[b, src, dst, :] and average over the 30 neighbors.
  // lanes 0..31 handle even k (channel = lane), lanes 32..63 odd k.
  float acc = 0.0f;
  const int half = lane >> 5;
  const int c = lane & 31;
  const int base_b = b * LSEQ;
#pragma unroll
  for (int itr = 0; itr < KNN / 2; ++itr) {
    int k = itr * 2 + half;
    int j = nbr[w][k];
    acc += pair_feat[((base_b + j) * LSEQ + il) * 32 + c];
  }
  float other = __shfl_xor(acc, 32, 64);
  float tot = acc + other;
  if (lane < 32) g_agg[i * 33 + c] = tot * (1.0f / KNN);

  // mean initial distance over neighbors
  float dval = 0.0f;
  if (lane < KNN) {
    int j = nbr[w][lane];
    float dx = xi - sx[j], dy = yi - sy[j], dz = zi - sz[j];
    dval = sqrtf(dx * dx + dy * dy + dz * dz);
  }
#pragma unroll
  for (int off = 32; off >= 1; off >>= 1) dval += __shfl_xor(dval, off, 64);
  if (lane == 0) g_agg[i * 33 + 32] = dval * (1.0f / KNN);
}

// ---------------------------------------------------------------------------
// Kernel 2: 4 layers of the node MLP, fused (per-node chain, no grid sync).
//   x <- relu([x, agg] @ w1[l] + b1[l]) @ w2[l] + b2[l]
// 16 nodes/block, 256 blocks (all CUs), 128 threads, 4x4 register tiles
// (8 ds_read_b128 per 128 VALU-cyc of FMA — best DS:VALU ratio at this M).
// Weight chunks (32 K-rows) staged global->reg->LDS with next-chunk prefetch
// issued before the barrier so L2 latency hides under compute (T14).
// K=161 handled as 5 chunks of 32 (rows 0..159) + explicit row-160 rank-1
// term (no zero padding, -16% GEMM1 staging/compute vs padded 192).
// ---------------------------------------------------------------------------
#define MT 16      // nodes per block
#define NFS 164    // nf row stride (161 used; 164*4B = 41*16B -> b128-aligned rows)
#define HS 132
#define WSS 132
#define NCHUNK 36  // 4 layers * (5 W1 + 4 W2) chunks of 32 K-rows

__global__ __launch_bounds__(128) void node_mlp_kernel(
    const float* __restrict__ res_feat,
    const float* __restrict__ w1, const float* __restrict__ b1,
    const float* __restrict__ w2, const float* __restrict__ b2,
    float* __restrict__ out) {
  __shared__ float nf[MT * NFS];     // [16][164]: x(0..127) | agg(128..160)
  __shared__ float hb[MT * HS];      // [16][132]: hidden
  __shared__ float wbuf[32 * WSS];   // [32][132]: weight K-chunk
  const int tid = threadIdx.x;       // 0..127
  const int node0 = blockIdx.x * MT;
  const int tx = tid & 31, ty = tid >> 5;   // ty 0..3
  const int c0 = tx * 4, r0 = ty * 4;       // 4x4 micro-tile

  // stage x tile (coalesced float4): 16*32 = 512 float4, 4 rounds
#pragma unroll
  for (int q = 0; q < 4; ++q) {
    int f4 = tid + 128 * q;
    int r = f4 >> 5, c4 = f4 & 31;
    *(float4*)&nf[r * NFS + c4 * 4] =
        *(const float4*)&res_feat[(node0 + r) * 128 + c4 * 4];
  }
  // stage agg tile (cols 128..160)
  for (int idx = tid; idx < MT * 33; idx += 128) {
    int r = idx / 33, cc = idx - r * 33;
    nf[r * NFS + 128 + cc] = g_agg[(node0 + r) * 33 + cc];
  }

  // ---- global chunk schedule: g = l*9 + (0..4 -> W1 rows 32g', 5..8 -> W2) ----
  auto chunk_ptr = [&](int g) -> const float* {
    int l = g / 9, r = g - l * 9;
    return (r < 5) ? (w1 + (l * 161 + r * 32) * 128)
                   : (w2 + (l * 128 + (r - 5) * 32) * 128);
  };
  // per-thread staging coords: chunk is 32 rows x 32 float4, 8 per thread
  float4 pre[8];
  {
    const float* cp = chunk_ptr(0);
#pragma unroll
    for (int q = 0; q < 8; ++q) {
      int f4 = tid + 128 * q;
      pre[q] = *(const float4*)&cp[(f4 >> 5) * 128 + (f4 & 31) * 4];
    }
  }

  int g = 0;
  for (int l = 0; l < 4; ++l) {
    // row-160 (dist-agg) weight row, issued early to hide L2 latency
    float4 w160 = *(const float4*)&w1[(l * 161 + 160) * 128 + c0];

    // ---- GEMM1: h = relu(nf @ W1 + b1), rows 0..159 chunked + row160 term ----
    float4 acc[4];
    {
      float4 bin = *(const float4*)&b1[l * 128 + c0];
#pragma unroll
      for (int ii = 0; ii < 4; ++ii) acc[ii] = bin;
    }
    for (int kc = 0; kc < 5; ++kc, ++g) {
      __syncthreads();  // previous chunk's readers done with wbuf
#pragma unroll
      for (int q = 0; q < 8; ++q) {
        int f4 = tid + 128 * q;
        *(float4*)&wbuf[(f4 >> 5) * WSS + (f4 & 31) * 4] = pre[q];
      }
      if (g + 1 < NCHUNK) {         // prefetch next chunk; completes under compute
        const float* cp = chunk_ptr(g + 1);
#pragma unroll
        for (int q = 0; q < 8; ++q) {
          int f4 = tid + 128 * q;
          pre[q] = *(const float4*)&cp[(f4 >> 5) * 128 + (f4 & 31) * 4];
        }
      }
      __syncthreads();  // wbuf ready
#pragma unroll
      for (int k4 = 0; k4 < 8; ++k4) {
        float4 av[4], wv[4];
#pragma unroll
        for (int ii = 0; ii < 4; ++ii)
          av[ii] = *(const float4*)&nf[(r0 + ii) * NFS + kc * 32 + k4 * 4];
#pragma unroll
        for (int q = 0; q < 4; ++q)
          wv[q] = *(const float4*)&wbuf[(k4 * 4 + q) * WSS + c0];
#pragma unroll
        for (int ii = 0; ii < 4; ++ii) {
          const float* ap = (const float*)&av[ii];
#pragma unroll
          for (int q = 0; q < 4; ++q) {
            acc[ii].x = fmaf(ap[q], wv[q].x, acc[ii].x);
            acc[ii].y = fmaf(ap[q], wv[q].y, acc[ii].y);
            acc[ii].z = fmaf(ap[q], wv[q].z, acc[ii].z);
            acc[ii].w = fmaf(ap[q], wv[q].w, acc[ii].w);
          }
        }
      }
    }
    // append K-row 160 (rel-dist agg column), then relu -> hidden tile
#pragma unroll
    for (int ii = 0; ii < 4; ++ii) {
      float a160 = nf[(r0 + ii) * NFS + 160];
      float4 v = acc[ii];
      v.x = fmaxf(fmaf(a160, w160.x, v.x), 0.0f);
      v.y = fmaxf(fmaf(a160, w160.y, v.y), 0.0f);
      v.z = fmaxf(fmaf(a160, w160.z, v.z), 0.0f);
      v.w = fmaxf(fmaf(a160, w160.w, v.w), 0.0f);
      *(float4*)&hb[(r0 + ii) * HS + c0] = v;
    }

    // ---- GEMM2: x = h @ W2 + b2, K = 128 = 4 chunks ----
    float4 acc2[4];
    {
      float4 bin2 = *(const float4*)&b2[l * 128 + c0];
#pragma unroll
      for (int ii = 0; ii < 4; ++ii) acc2[ii] = bin2;
    }
    for (int kc = 0; kc < 4; ++kc, ++g) {
      __syncthreads();  // also orders hb writes before hb reads
#pragma unroll
      for (int q = 0; q < 8; ++q) {
        int f4 = tid + 128 * q;
        *(float4*)&wbuf[(f4 >> 5) * WSS + (f4 & 31) * 4] = pre[q];
      }
      if (g + 1 < NCHUNK) {
        const float* cp = chunk_ptr(g + 1);   // last GEMM2 chunk prefetches next layer's W1
#pragma unroll
        for (int q = 0; q < 8; ++q) {
          int f4 = tid + 128 * q;
          pre[q] = *(const float4*)&cp[(f4 >> 5) * 128 + (f4 & 31) * 4];
        }
      }
      __syncthreads();
#pragma unroll
      for (int k4 = 0; k4 < 8; ++k4) {
        float4 av[4], wv[4];
#pragma unroll
        for (int ii = 0; ii < 4; ++ii)
          av[ii] = *(const float4*)&hb[(r0 + ii) * HS + kc * 32 + k4 * 4];
#pragma unroll
        for (int q = 0; q < 4; ++q)
          wv[q] = *(const float4*)&wbuf[(k4 * 4 + q) * WSS + c0];
#pragma unroll
        for (int ii = 0; ii < 4; ++ii) {
          const float* ap = (const float*)&av[ii];
#pragma unroll
          for (int q = 0; q < 4; ++q) {
            acc2[ii].x = fmaf(ap[q], wv[q].x, acc2[ii].x);
            acc2[ii].y = fmaf(ap[q], wv[q].y, acc2[ii].y);
            acc2[ii].z = fmaf(ap[q], wv[q].z, acc2[ii].z);
            acc2[ii].w = fmaf(ap[q], wv[q].w, acc2[ii].w);
          }
        }
      }
    }
    if (l < 3) {
      // write next-layer x into nf (cols 0..127; agg cols untouched).
      // next read of these cells is after the next chunk loop's barriers.
#pragma unroll
      for (int ii = 0; ii < 4; ++ii)
        *(float4*)&nf[(r0 + ii) * NFS + c0] = acc2[ii];
    } else {
#pragma unroll
      for (int ii = 0; ii < 4; ++ii)
        *(float4*)&out[(node0 + r0 + ii) * 128 + c0] = acc2[ii];
    }
  }
}

// ---------------------------------------------------------------------------
extern "C" void kernel_launch(void* const* d_in, const int* in_sizes, int n_in,
                              void* d_out, int out_size, void* d_ws, size_t ws_size,
                              hipStream_t stream) {
  // setup_inputs order:
  // 0:R 1:t 2:res_feat 3:pair_feat 4:mask_res 5:coord_w1 6:coord_b1 7:coord_w2
  // 8:coord_b2 9:node_w1 10:node_b1 11:node_w2 12:node_b2
  // (R, mask_res and all coord_* are dead code for the returned x.)
  const float* t         = (const float*)d_in[1];
  const float* res_feat  = (const float*)d_in[2];
  const float* pair_feat = (const float*)d_in[3];
  const float* nw1       = (const float*)d_in[9];
  const float* nb1       = (const float*)d_in[10];
  const float* nw2       = (const float*)d_in[11];
  const float* nb2       = (const float*)d_in[12];
  float* out = (float*)d_out;
  (void)in_sizes; (void)n_in; (void)out_size; (void)d_ws; (void)ws_size;

  knn_agg_kernel<<<1024, 256, 0, stream>>>(t, pair_feat);
  node_mlp_kernel<<<NNODES / MT, 128, 0, stream>>>(res_feat, nw1, nb1, nw2, nb2, out);
}